// Round 1
// baseline (362.507 us; speedup 1.0000x reference)
//
#include <hip/hip_runtime.h>

#define N_ROWS   65536
#define N_CLASSES 1000
#define N_QUADS   250            // 1000 f32 = 250 float4 per row

__global__ void zero_out_kernel(float* out) {
    if (threadIdx.x == 0) out[0] = 0.0f;
}

__global__ __launch_bounds__(256, 8)
void cosine_loss_kernel(const float* __restrict__ pred,
                        const int*   __restrict__ tgt,
                        float*       __restrict__ out) {
    const int lane     = threadIdx.x & 63;
    const int wave_in_blk = threadIdx.x >> 6;
    const int wave_id  = blockIdx.x * 4 + wave_in_blk;
    const int n_waves  = gridDim.x * 4;

    float acc = 0.0f;

    for (int row = wave_id; row < N_ROWS; row += n_waves) {
        const float4* rp = (const float4*)(pred + (size_t)row * N_CLASSES);
        const int t  = tgt[row];      // wave-uniform broadcast load
        const int tq = t >> 2;        // which float4 holds the target element
        const int tr = t & 3;

        float ss = 0.0f;
        float g  = 0.0f;
        #pragma unroll
        for (int i = 0; i < 4; ++i) {
            const int idx = lane + 64 * i;
            if (idx < N_QUADS) {
                float4 v = rp[idx];
                ss += v.x * v.x + v.y * v.y + v.z * v.z + v.w * v.w;
                if (idx == tq) {
                    g = (tr == 0) ? v.x : (tr == 1) ? v.y : (tr == 2) ? v.z : v.w;
                }
            }
        }

        // 64-lane butterfly reduction for ss and g (wave = 64 on CDNA!)
        #pragma unroll
        for (int off = 32; off > 0; off >>= 1) {
            ss += __shfl_xor(ss, off, 64);
            g  += __shfl_xor(g,  off, 64);
        }

        const float norm = sqrtf(ss);
        const float d    = 1.0f - norm;
        acc += -g / (norm + 1e-9f) + 0.1f * d * d;
    }

    // block-level reduction: 4 wave partials -> 1 atomic per block
    __shared__ float smem[4];
    if (lane == 0) smem[wave_in_blk] = acc;
    __syncthreads();
    if (threadIdx.x == 0) {
        const float s = smem[0] + smem[1] + smem[2] + smem[3];
        atomicAdd(out, s * (1.0f / (float)N_ROWS));
    }
}

extern "C" void kernel_launch(void* const* d_in, const int* in_sizes, int n_in,
                              void* d_out, int out_size, void* d_ws, size_t ws_size,
                              hipStream_t stream) {
    const float* pred = (const float*)d_in[0];
    const int*   tgt  = (const int*)d_in[1];
    float*       out  = (float*)d_out;

    zero_out_kernel<<<1, 64, 0, stream>>>(out);
    cosine_loss_kernel<<<2048, 256, 0, stream>>>(pred, tgt, out);
}

// Round 2
// 350.947 us; speedup vs baseline: 1.0329x; 1.0329x over previous
//
#include <hip/hip_runtime.h>

#define N_ROWS    65536
#define N_CLASSES 1000
#define N_QUADS   250          // 1000 f32 = 250 float4 per row
#define GRID      2048
#define WAVES_TOT (GRID * 4)   // 8192 waves, 8 rows/wave

__global__ __launch_bounds__(256, 4)
void cosine_loss_main(const float* __restrict__ pred,
                      const int*   __restrict__ tgt,
                      float*       __restrict__ partials) {
    const int lane   = threadIdx.x & 63;
    const int wiv    = threadIdx.x >> 6;
    const int waveId = blockIdx.x * 4 + wiv;

    float acc = 0.0f;   // per-lane accumulator; summed across lanes ONCE at the end

    // 65536 rows / 8192 waves = 8 rows per wave; unroll 2 rows per iteration
    // (stride 2*WAVES_TOT guarantees row1 = row0 + WAVES_TOT < N_ROWS always).
    #pragma unroll 1
    for (int r = waveId; r < N_ROWS; r += 2 * WAVES_TOT) {
        const int row0 = r;
        const int row1 = r + WAVES_TOT;
        const float4* rp0 = (const float4*)(pred + (size_t)row0 * N_CLASSES);
        const float4* rp1 = (const float4*)(pred + (size_t)row1 * N_CLASSES);
        const int t0 = tgt[row0];
        const int t1 = tgt[row1];

        // Issue all 8 loads (2 rows x 4 float4) before any reduction work.
        float4 va[4], vb[4];
        #pragma unroll
        for (int i = 0; i < 4; ++i) {
            const int idx = lane + 64 * i;
            va[i] = (idx < N_QUADS) ? rp0[idx] : make_float4(0.f, 0.f, 0.f, 0.f);
        }
        #pragma unroll
        for (int i = 0; i < 4; ++i) {
            const int idx = lane + 64 * i;
            vb[i] = (idx < N_QUADS) ? rp1[idx] : make_float4(0.f, 0.f, 0.f, 0.f);
        }

        const int tq0 = t0 >> 2, tr0 = t0 & 3;
        const int tq1 = t1 >> 2, tr1 = t1 & 3;

        float ss0 = 0.f, g0 = 0.f;
        float ss1 = 0.f, g1 = 0.f;
        #pragma unroll
        for (int i = 0; i < 4; ++i) {
            const int idx = lane + 64 * i;
            const float4 v = va[i];
            ss0 += v.x * v.x + v.y * v.y + v.z * v.z + v.w * v.w;
            if (idx == tq0)
                g0 = (tr0 == 0) ? v.x : (tr0 == 1) ? v.y : (tr0 == 2) ? v.z : v.w;
            const float4 w = vb[i];
            ss1 += w.x * w.x + w.y * w.y + w.z * w.z + w.w * w.w;
            if (idx == tq1)
                g1 = (tr1 == 0) ? w.x : (tr1 == 1) ? w.y : (tr1 == 2) ? w.z : w.w;
        }

        // Butterfly-reduce ONLY ss (two independent chains interleave/overlap).
        #pragma unroll
        for (int off = 32; off > 0; off >>= 1) {
            ss0 += __shfl_xor(ss0, off, 64);
            ss1 += __shfl_xor(ss1, off, 64);
        }

        // norm is wave-uniform; g stays per-lane (only one lane nonzero).
        const float norm0 = __builtin_amdgcn_sqrtf(ss0);
        const float norm1 = __builtin_amdgcn_sqrtf(ss1);
        acc -= g0 * __builtin_amdgcn_rcpf(norm0 + 1e-9f);
        acc -= g1 * __builtin_amdgcn_rcpf(norm1 + 1e-9f);
        if (lane == 0) {
            const float d0 = 1.0f - norm0;
            const float d1 = 1.0f - norm1;
            acc += 0.1f * (d0 * d0 + d1 * d1);
        }
    }

    // One final cross-lane reduction per wave.
    #pragma unroll
    for (int off = 32; off > 0; off >>= 1)
        acc += __shfl_xor(acc, off, 64);

    __shared__ float smem[4];
    if (lane == 0) smem[wiv] = acc;
    __syncthreads();
    if (threadIdx.x == 0)
        partials[blockIdx.x] = smem[0] + smem[1] + smem[2] + smem[3];
}

__global__ __launch_bounds__(256)
void cosine_loss_finish(const float* __restrict__ partials,
                        float*       __restrict__ out) {
    const int lane = threadIdx.x & 63;
    const int wiv  = threadIdx.x >> 6;
    float s = 0.f;
    #pragma unroll
    for (int k = 0; k < GRID / 256; ++k)
        s += partials[threadIdx.x + 256 * k];
    #pragma unroll
    for (int off = 32; off > 0; off >>= 1)
        s += __shfl_xor(s, off, 64);
    __shared__ float smem[4];
    if (lane == 0) smem[wiv] = s;
    __syncthreads();
    if (threadIdx.x == 0)
        out[0] = (smem[0] + smem[1] + smem[2] + smem[3]) * (1.0f / (float)N_ROWS);
}

extern "C" void kernel_launch(void* const* d_in, const int* in_sizes, int n_in,
                              void* d_out, int out_size, void* d_ws, size_t ws_size,
                              hipStream_t stream) {
    const float* pred = (const float*)d_in[0];
    const int*   tgt  = (const int*)d_in[1];
    float*       out  = (float*)d_out;
    float*       partials = (float*)d_ws;   // 2048 floats = 8 KB scratch

    cosine_loss_main<<<GRID, 256, 0, stream>>>(pred, tgt, partials);
    cosine_loss_finish<<<1, 256, 0, stream>>>(partials, out);
}

// Round 3
// 323.477 us; speedup vs baseline: 1.1207x; 1.0849x over previous
//
#include <hip/hip_runtime.h>

#define N_ROWS    65536
#define N_CLASSES 1000
#define N_QUADS   250          // 1000 f32 = 250 float4 per row
#define GRID      2048
#define WAVES_TOT (GRID * 4)   // 8192 waves, 8 rows/wave, 2 iterations of 4 rows

typedef float v4f __attribute__((ext_vector_type(4)));

__global__ __launch_bounds__(256, 4)
void cosine_loss_main(const float* __restrict__ pred,
                      const int*   __restrict__ tgt,
                      float*       __restrict__ partials) {
    const int lane   = threadIdx.x & 63;
    const int wiv    = threadIdx.x >> 6;
    const int waveId = blockIdx.x * 4 + wiv;

    float acc = 0.0f;   // per-lane; cross-lane summed ONCE at the end

    // N_ROWS == 8 * WAVES_TOT, so exactly 2 full iterations of 4 rows/wave.
    #pragma unroll 1
    for (int r = waveId; r < N_ROWS; r += 4 * WAVES_TOT) {
        int  t[4];
        v4f  v[4][4];            // [row][quad] — 16 dwordx4 loads in flight

        #pragma unroll
        for (int j = 0; j < 4; ++j) {
            const int row = r + j * WAVES_TOT;
            const v4f* rp = (const v4f*)(pred + (size_t)row * N_CLASSES);
            t[j] = tgt[row];     // wave-uniform -> scalar load
            // chunks 0..2: lane+128 <= 191 < 250, always in bounds
            v[j][0] = __builtin_nontemporal_load(&rp[lane]);
            v[j][1] = __builtin_nontemporal_load(&rp[lane + 64]);
            v[j][2] = __builtin_nontemporal_load(&rp[lane + 128]);
            v[j][3] = (lane < N_QUADS - 192)
                        ? __builtin_nontemporal_load(&rp[lane + 192])
                        : (v4f){0.f, 0.f, 0.f, 0.f};
        }

        float ss[4], g[4];
        #pragma unroll
        for (int j = 0; j < 4; ++j) {
            const int tq = t[j] >> 2, tr = t[j] & 3;
            ss[j] = 0.f; g[j] = 0.f;
            #pragma unroll
            for (int i = 0; i < 4; ++i) {
                const int idx = lane + 64 * i;
                const v4f w = v[j][i];
                ss[j] += w.x * w.x + w.y * w.y + w.z * w.z + w.w * w.w;
                if (idx == tq)
                    g[j] = (tr == 0) ? w.x : (tr == 1) ? w.y : (tr == 2) ? w.z : w.w;
            }
        }

        // 4 independent butterfly chains (ss only) — interleaved, latency overlaps.
        #pragma unroll
        for (int off = 32; off > 0; off >>= 1) {
            #pragma unroll
            for (int j = 0; j < 4; ++j)
                ss[j] += __shfl_xor(ss[j], off, 64);
        }

        #pragma unroll
        for (int j = 0; j < 4; ++j) {
            const float norm = __builtin_amdgcn_sqrtf(ss[j]);
            acc -= g[j] * __builtin_amdgcn_rcpf(norm + 1e-9f);
            if (lane == 0) {
                const float d = 1.0f - norm;
                acc += 0.1f * d * d;
            }
        }
    }

    // One cross-lane reduction per wave.
    #pragma unroll
    for (int off = 32; off > 0; off >>= 1)
        acc += __shfl_xor(acc, off, 64);

    __shared__ float smem[4];
    if (lane == 0) smem[wiv] = acc;
    __syncthreads();
    if (threadIdx.x == 0)
        partials[blockIdx.x] = smem[0] + smem[1] + smem[2] + smem[3];
}

__global__ __launch_bounds__(256)
void cosine_loss_finish(const float* __restrict__ partials,
                        float*       __restrict__ out) {
    const int lane = threadIdx.x & 63;
    const int wiv  = threadIdx.x >> 6;
    float s = 0.f;
    #pragma unroll
    for (int k = 0; k < GRID / 256; ++k)
        s += partials[threadIdx.x + 256 * k];
    #pragma unroll
    for (int off = 32; off > 0; off >>= 1)
        s += __shfl_xor(s, off, 64);
    __shared__ float smem[4];
    if (lane == 0) smem[wiv] = s;
    __syncthreads();
    if (threadIdx.x == 0)
        out[0] = (smem[0] + smem[1] + smem[2] + smem[3]) * (1.0f / (float)N_ROWS);
}

extern "C" void kernel_launch(void* const* d_in, const int* in_sizes, int n_in,
                              void* d_out, int out_size, void* d_ws, size_t ws_size,
                              hipStream_t stream) {
    const float* pred = (const float*)d_in[0];
    const int*   tgt  = (const int*)d_in[1];
    float*       out  = (float*)d_out;
    float*       partials = (float*)d_ws;   // 2048 floats = 8 KB scratch

    cosine_loss_main<<<GRID, 256, 0, stream>>>(pred, tgt, partials);
    cosine_loss_finish<<<1, 256, 0, stream>>>(partials, out);
}